// Round 1
// baseline (874.756 us; speedup 1.0000x reference)
//
#include <hip/hip_runtime.h>

// LightGCN: 3 layers of normalized scatter-add over 1M edges, 150000x64 fp32 nodes.
// d_in[0]: edge_index int32 [2][1M]; d_in[1]: emb_weight fp32 [150000][64]
// d_out: (user_emb ++ item_emb) = full 150000x64 acc/4, fp32.

constexpr int kNodes = 150000;
constexpr int kDim   = 64;
constexpr int kEdges = 1000000;
constexpr int kEmbFloats = kNodes * kDim;      // 9,600,000
constexpr int kEmb4      = kEmbFloats / 4;     // 2,400,000

__global__ __launch_bounds__(256) void deg_kernel(const int* __restrict__ dst,
                                                  float* __restrict__ deg) {
    int e = blockIdx.x * 256 + threadIdx.x;
    if (e < kEdges) unsafeAtomicAdd(&deg[dst[e]], 1.0f);
}

__global__ __launch_bounds__(256) void dinv_kernel(float* __restrict__ deg) {
    int n = blockIdx.x * 256 + threadIdx.x;
    if (n < kNodes) {
        float d = deg[n];
        deg[n] = (d > 0.0f) ? rsqrtf(d) : 0.0f;
    }
}

__global__ __launch_bounds__(256) void norm_kernel(const int* __restrict__ src,
                                                   const int* __restrict__ dst,
                                                   const float* __restrict__ dinv,
                                                   float* __restrict__ norm) {
    int e = blockIdx.x * 256 + threadIdx.x;
    if (e < kEdges) norm[e] = dinv[src[e]] * dinv[dst[e]];
}

__global__ __launch_bounds__(256) void copy4_kernel(const float4* __restrict__ in,
                                                    float4* __restrict__ out) {
    int i = blockIdx.x * 256 + threadIdx.x;
    if (i < kEmb4) out[i] = in[i];
}

// One lane per (edge, dim): wave's 64 lanes cover one edge's full row.
__global__ __launch_bounds__(256) void scatter_kernel(const int* __restrict__ src,
                                                      const int* __restrict__ dst,
                                                      const float* __restrict__ norm,
                                                      const float* __restrict__ x,
                                                      float* __restrict__ y) {
    int t = blockIdx.x * 256 + threadIdx.x;
    int e = t >> 6;
    int d = t & 63;
    if (e < kEdges) {
        int s  = src[e];
        int dd = dst[e];
        float v = x[s * kDim + d] * norm[e];
        unsafeAtomicAdd(&y[dd * kDim + d], v);
    }
}

__global__ __launch_bounds__(256) void add_kernel(float4* __restrict__ out,
                                                  const float4* __restrict__ emb) {
    int i = blockIdx.x * 256 + threadIdx.x;
    if (i < kEmb4) {
        float4 a = out[i];
        float4 b = emb[i];
        a.x += b.x; a.y += b.y; a.z += b.z; a.w += b.w;
        out[i] = a;
    }
}

__global__ __launch_bounds__(256) void add_scale_kernel(float4* __restrict__ out,
                                                        const float4* __restrict__ emb) {
    int i = blockIdx.x * 256 + threadIdx.x;
    if (i < kEmb4) {
        float4 a = out[i];
        float4 b = emb[i];
        a.x = (a.x + b.x) * 0.25f;
        a.y = (a.y + b.y) * 0.25f;
        a.z = (a.z + b.z) * 0.25f;
        a.w = (a.w + b.w) * 0.25f;
        out[i] = a;
    }
}

extern "C" void kernel_launch(void* const* d_in, const int* in_sizes, int n_in,
                              void* d_out, int out_size, void* d_ws, size_t ws_size,
                              hipStream_t stream) {
    const int*   edge  = (const int*)d_in[0];
    const int*   src   = edge;
    const int*   dst   = edge + kEdges;
    const float* emb_w = (const float*)d_in[1];
    float*       out   = (float*)d_out;

    // Workspace layout (all re-poisoned 0xAA before each call -> must re-init):
    //   deg/dinv : kNodes floats        @ 0         (600 KB, pad to 1 MB)
    //   norm     : kEdges floats        @ 1 MB      (4 MB, pad to 5 MB)
    //   embA     : kEmbFloats floats    @ 5 MB      (38.4 MB)
    //   embB     : kEmbFloats floats    @ 5 MB + 38.4 MB
    char* ws = (char*)d_ws;
    float* deg  = (float*)(ws);
    float* norm = (float*)(ws + (1u << 20));
    float* embA = (float*)(ws + (5u << 20));
    float* embB = (float*)(ws + (5u << 20) + (size_t)kEmbFloats * 4);

    const int edgeBlocks  = (kEdges + 255) / 256;
    const int nodeBlocks  = (kNodes + 255) / 256;
    const int emb4Blocks  = (kEmb4 + 255) / 256;
    const int scatBlocks  = (kEdges * kDim) / 256;   // 250000

    // Degree -> dinv -> per-edge norm
    hipMemsetAsync(deg, 0, (size_t)kNodes * 4, stream);
    deg_kernel<<<edgeBlocks, 256, 0, stream>>>(dst, deg);
    dinv_kernel<<<nodeBlocks, 256, 0, stream>>>(deg);
    norm_kernel<<<edgeBlocks, 256, 0, stream>>>(src, dst, deg, norm);

    // acc = emb_weight
    copy4_kernel<<<emb4Blocks, 256, 0, stream>>>((const float4*)emb_w, (float4*)out);

    // 3 propagation layers, ping-pong embA/embB, accumulate into out
    const float* cur = emb_w;
    float* bufs[2] = {embA, embB};
    for (int l = 0; l < 3; ++l) {
        float* nxt = bufs[l & 1];
        hipMemsetAsync(nxt, 0, (size_t)kEmbFloats * 4, stream);
        scatter_kernel<<<scatBlocks, 256, 0, stream>>>(src, dst, norm, cur, nxt);
        if (l < 2) {
            add_kernel<<<emb4Blocks, 256, 0, stream>>>((float4*)out, (const float4*)nxt);
        } else {
            add_scale_kernel<<<emb4Blocks, 256, 0, stream>>>((float4*)out, (const float4*)nxt);
        }
        cur = nxt;
    }
}

// Round 2
// 464.333 us; speedup vs baseline: 1.8839x; 1.8839x over previous
//
#include <hip/hip_runtime.h>

// LightGCN on MI355X. Gather formulation (no fp32 scatter atomics):
// per-call CSR build (hist -> scan -> fill (src,norm) pairs by dst),
// then 3 layers of: one wave per node, 64 lanes = 64 dims,
// h[d] = sum_{e in N(d)} norm[e] * x[src[e]], acc fused in epilogue.
//
// d_in[0]: edge_index int32 [2][1M]  (src = first 1M, dst = next 1M)
// d_in[1]: emb_weight fp32 [150000][64]
// d_out  : full 150000x64 fp32 = (emb + h1 + h2 + h3)/4

constexpr int kNodes     = 150000;
constexpr int kDim       = 64;
constexpr int kEdges     = 1000000;
constexpr int kEmbFloats = kNodes * kDim;          // 9,600,000
constexpr int kScanBlk   = (kNodes + 255) / 256;   // 586

// ---------------- prologue: degree histogram + dinv ----------------

__global__ __launch_bounds__(256) void hist_kernel(const int* __restrict__ dst,
                                                   int* __restrict__ counts) {
    int e = blockIdx.x * 256 + threadIdx.x;
    if (e < kEdges) atomicAdd(&counts[dst[e]], 1);
}

__global__ __launch_bounds__(256) void dinv_kernel(const int* __restrict__ counts,
                                                   float* __restrict__ dinv) {
    int n = blockIdx.x * 256 + threadIdx.x;
    if (n < kNodes) {
        int d = counts[n];
        dinv[n] = (d > 0) ? rsqrtf((float)d) : 0.0f;
    }
}

// ---------------- exclusive scan over counts (3 kernels) ----------------

__global__ __launch_bounds__(256) void scan_block_kernel(const int* __restrict__ counts,
                                                         int* __restrict__ off,
                                                         int* __restrict__ sums) {
    __shared__ int lds[256];
    int n = blockIdx.x * 256 + threadIdx.x;
    int c = (n < kNodes) ? counts[n] : 0;
    lds[threadIdx.x] = c;
    __syncthreads();
    int v = c;
    for (int s = 1; s < 256; s <<= 1) {
        int t = (threadIdx.x >= s) ? lds[threadIdx.x - s] : 0;
        __syncthreads();
        v += t;
        lds[threadIdx.x] = v;
        __syncthreads();
    }
    if (n < kNodes) off[n] = v - c;                 // exclusive within block
    if (threadIdx.x == 255) sums[blockIdx.x] = v;   // block total
}

__global__ __launch_bounds__(1024) void scan_sums_kernel(int* __restrict__ sums) {
    __shared__ int lds[1024];
    int v = (threadIdx.x < kScanBlk) ? sums[threadIdx.x] : 0;
    lds[threadIdx.x] = v;
    __syncthreads();
    int acc = v;
    for (int s = 1; s < 1024; s <<= 1) {
        int t = (threadIdx.x >= s) ? lds[threadIdx.x - s] : 0;
        __syncthreads();
        acc += t;
        lds[threadIdx.x] = acc;
        __syncthreads();
    }
    if (threadIdx.x < kScanBlk) sums[threadIdx.x] = acc - v;  // exclusive
}

__global__ __launch_bounds__(256) void scan_fixup_kernel(int* __restrict__ off,
                                                         int* __restrict__ cur,
                                                         const int* __restrict__ sums) {
    int n = blockIdx.x * 256 + threadIdx.x;
    if (n < kNodes) {
        int o = off[n] + sums[blockIdx.x];
        off[n] = o;
        cur[n] = o;
    }
}

// ---------------- fill CSR payload: (src, norm) pairs bucketed by dst ----------------

__global__ __launch_bounds__(256) void fill_kernel(const int* __restrict__ src,
                                                   const int* __restrict__ dst,
                                                   const float* __restrict__ dinv,
                                                   int* __restrict__ cur,
                                                   int2* __restrict__ pairs) {
    int e = blockIdx.x * 256 + threadIdx.x;
    if (e < kEdges) {
        int s = src[e];
        int d = dst[e];
        int p = atomicAdd(&cur[d], 1);
        pairs[p] = make_int2(s, __float_as_int(dinv[s] * dinv[d]));
    }
}

// ---------------- gather layer: one wave per node ----------------
// h[node] = sum norm*x[src]; accOut[node] = (accIn[node] + h) * scale

__global__ __launch_bounds__(256) void gather_kernel(const int* __restrict__ off,
                                                     const int* __restrict__ counts,
                                                     const int2* __restrict__ pairs,
                                                     const float* __restrict__ x,
                                                     float* __restrict__ h,
                                                     const float* __restrict__ accIn,
                                                     float* __restrict__ accOut,
                                                     float scale,
                                                     int writeH) {
    int t    = blockIdx.x * 256 + threadIdx.x;
    int node = t >> 6;
    int lane = t & 63;
    if (node >= kNodes) return;

    int b   = off[node];
    int cnt = counts[node];

    float s = 0.0f;
    for (int base = 0; base < cnt; base += 64) {
        int m = cnt - base;
        if (m > 64) m = 64;
        // coalesced wave-wide read of up to 64 edge payloads, then broadcast
        int2 myp = (lane < m) ? pairs[b + base + lane] : make_int2(0, 0);
        for (int i = 0; i < m; ++i) {
            int   si = __shfl(myp.x, i);
            float nv = __int_as_float(__shfl(myp.y, i));
            s = fmaf(x[(size_t)si * kDim + lane], nv, s);
        }
    }

    size_t idx = (size_t)node * kDim + lane;
    if (writeH) h[idx] = s;
    float a = accIn[idx] + s;
    accOut[idx] = a * scale;
}

// ---------------- launch ----------------

extern "C" void kernel_launch(void* const* d_in, const int* in_sizes, int n_in,
                              void* d_out, int out_size, void* d_ws, size_t ws_size,
                              hipStream_t stream) {
    const int*   edge  = (const int*)d_in[0];
    const int*   src   = edge;
    const int*   dst   = edge + kEdges;
    const float* emb_w = (const float*)d_in[1];
    float*       out   = (float*)d_out;

    // Workspace layout (bytes; everything re-poisoned 0xAA each call):
    //   counts : @0          150000*4 = 600000
    //   dinv   : @600000     600000
    //   off    : @1200000    600000
    //   cur    : @1800000    600000
    //   sums   : @2400000    586*4 (pad)
    //   pairs  : @2402352    1M * 8B = 8,000,000
    //   embA   : @10402352   38,400,000
    //   embB   : @48802352   38,400,000   (end ~87.2 MB)
    char*  ws     = (char*)d_ws;
    int*   counts = (int*)(ws);
    float* dinv   = (float*)(ws + 600000);
    int*   off    = (int*)(ws + 1200000);
    int*   cur    = (int*)(ws + 1800000);
    int*   sums   = (int*)(ws + 2400000);
    int2*  pairs  = (int2*)(ws + 2402352);
    float* embA   = (float*)(ws + 10402352);
    float* embB   = (float*)(ws + 48802352);

    const int edgeBlocks   = (kEdges + 255) / 256;
    const int nodeBlocks   = kScanBlk;
    const int gatherBlocks = (kNodes * kDim + 255) / 256;  // 37500

    // CSR build
    hipMemsetAsync(counts, 0, (size_t)kNodes * 4, stream);
    hist_kernel<<<edgeBlocks, 256, 0, stream>>>(dst, counts);
    dinv_kernel<<<nodeBlocks, 256, 0, stream>>>(counts, dinv);
    scan_block_kernel<<<nodeBlocks, 256, 0, stream>>>(counts, off, sums);
    scan_sums_kernel<<<1, 1024, 0, stream>>>(sums);
    scan_fixup_kernel<<<nodeBlocks, 256, 0, stream>>>(off, cur, sums);
    fill_kernel<<<edgeBlocks, 256, 0, stream>>>(src, dst, dinv, cur, pairs);

    // Layer 1: h1 = conv(emb_w); out = emb_w + h1
    gather_kernel<<<gatherBlocks, 256, 0, stream>>>(off, counts, pairs, emb_w,
                                                    embA, emb_w, out, 1.0f, 1);
    // Layer 2: h2 = conv(h1); out += h2
    gather_kernel<<<gatherBlocks, 256, 0, stream>>>(off, counts, pairs, embA,
                                                    embB, out, out, 1.0f, 1);
    // Layer 3: h3 = conv(h2); out = (out + h3) / 4   (h3 not stored)
    gather_kernel<<<gatherBlocks, 256, 0, stream>>>(off, counts, pairs, embB,
                                                    embA, out, out, 0.25f, 0);
}

// Round 3
// 380.707 us; speedup vs baseline: 2.2977x; 1.2197x over previous
//
#include <hip/hip_runtime.h>

// LightGCN on MI355X. Gather formulation with float4-vectorized rows:
// CSR build (hist -> scan -> fill (src,norm) pairs by dst), then 3 layers of
// one wave per node: 16 lanes x float4 = one 64-dim row, 4 edge-slots/wave.
//
// d_in[0]: edge_index int32 [2][1M]  (src = first 1M, dst = next 1M)
// d_in[1]: emb_weight fp32 [150000][64]
// d_out  : full 150000x64 fp32 = (emb + h1 + h2 + h3)/4

constexpr int kNodes     = 150000;
constexpr int kDim       = 64;
constexpr int kEdges     = 1000000;
constexpr int kRow4      = kDim / 4;               // 16 float4 per row
constexpr int kScanBlk   = (kNodes + 255) / 256;   // 586

// ---------------- prologue: degree histogram ----------------

__global__ __launch_bounds__(256) void hist_kernel(const int* __restrict__ dst,
                                                   int* __restrict__ counts) {
    int e = blockIdx.x * 256 + threadIdx.x;
    if (e < kEdges) atomicAdd(&counts[dst[e]], 1);
}

// ---------------- exclusive scan over counts ----------------

__global__ __launch_bounds__(256) void scan_block_kernel(const int* __restrict__ counts,
                                                         int* __restrict__ off,
                                                         int* __restrict__ sums) {
    __shared__ int lds[256];
    int n = blockIdx.x * 256 + threadIdx.x;
    int c = (n < kNodes) ? counts[n] : 0;
    lds[threadIdx.x] = c;
    __syncthreads();
    int v = c;
    for (int s = 1; s < 256; s <<= 1) {
        int t = (threadIdx.x >= s) ? lds[threadIdx.x - s] : 0;
        __syncthreads();
        v += t;
        lds[threadIdx.x] = v;
        __syncthreads();
    }
    if (n < kNodes) off[n] = v - c;                 // exclusive within block
    if (threadIdx.x == 255) sums[blockIdx.x] = v;   // block total
}

__global__ __launch_bounds__(1024) void scan_sums_kernel(int* __restrict__ sums) {
    __shared__ int lds[1024];
    int v = (threadIdx.x < kScanBlk) ? sums[threadIdx.x] : 0;
    lds[threadIdx.x] = v;
    __syncthreads();
    int acc = v;
    for (int s = 1; s < 1024; s <<= 1) {
        int t = (threadIdx.x >= s) ? lds[threadIdx.x - s] : 0;
        __syncthreads();
        acc += t;
        lds[threadIdx.x] = acc;
        __syncthreads();
    }
    if (threadIdx.x < kScanBlk) sums[threadIdx.x] = acc - v;  // exclusive
}

// fixup + dinv fused (both per-node)
__global__ __launch_bounds__(256) void scan_fixup_kernel(int* __restrict__ off,
                                                         int* __restrict__ cur,
                                                         const int* __restrict__ sums,
                                                         const int* __restrict__ counts,
                                                         float* __restrict__ dinv) {
    int n = blockIdx.x * 256 + threadIdx.x;
    if (n < kNodes) {
        int o = off[n] + sums[blockIdx.x];
        off[n] = o;
        cur[n] = o;
        int c = counts[n];
        dinv[n] = (c > 0) ? rsqrtf((float)c) : 0.0f;
    }
}

// ---------------- fill CSR payload: (src, norm) pairs bucketed by dst ----------------

__global__ __launch_bounds__(256) void fill_kernel(const int* __restrict__ src,
                                                   const int* __restrict__ dst,
                                                   const float* __restrict__ dinv,
                                                   int* __restrict__ cur,
                                                   int2* __restrict__ pairs) {
    int e = blockIdx.x * 256 + threadIdx.x;
    if (e < kEdges) {
        int s = src[e];
        int d = dst[e];
        int p = atomicAdd(&cur[d], 1);
        pairs[p] = make_int2(s, __float_as_int(dinv[s] * dinv[d]));
    }
}

// ---------------- gather layer: one wave per node, float4 rows ----------------
// lane = g*16 + q : g = edge slot (0..3), q = float4 index within the row.
// h[node] = sum norm*x[src]; accOut[node] = (accIn[node] + h) * scale

__global__ __launch_bounds__(256) void gather_kernel(const int* __restrict__ off,
                                                     const int* __restrict__ counts,
                                                     const int2* __restrict__ pairs,
                                                     const float4* __restrict__ x4,
                                                     float4* __restrict__ h4,
                                                     const float4* __restrict__ accIn4,
                                                     float4* __restrict__ accOut4,
                                                     float scale,
                                                     int writeH) {
    int t    = blockIdx.x * 256 + threadIdx.x;
    int node = t >> 6;          // grid covers exactly kNodes*64 threads
    int lane = t & 63;
    int q    = lane & 15;
    int g    = lane >> 4;

    int b   = off[node];
    int cnt = counts[node];

    float4 s = make_float4(0.f, 0.f, 0.f, 0.f);
    for (int base = 0; base < cnt; base += 64) {
        int m = cnt - base;
        if (m > 64) m = 64;
        // coalesced wave-wide read of up to 64 edge payloads
        int2 myp = (lane < m) ? pairs[b + base + lane] : make_int2(0, 0);
        for (int i = 0; i < m; i += 4) {
            int  slot = i + g;               // per-lane source slot
            bool act  = slot < m;
            int  si   = __shfl(myp.x, slot); // ds_bpermute, per-lane index
            int  nvi  = __shfl(myp.y, slot);
            si = act ? si : 0;
            float nv = act ? __int_as_float(nvi) : 0.0f;
            float4 xv = x4[(size_t)si * kRow4 + q];
            s.x = fmaf(xv.x, nv, s.x);
            s.y = fmaf(xv.y, nv, s.y);
            s.z = fmaf(xv.z, nv, s.z);
            s.w = fmaf(xv.w, nv, s.w);
        }
    }

    // reduce across the 4 edge slots (lanes q, q+16, q+32, q+48)
    s.x += __shfl_xor(s.x, 16); s.y += __shfl_xor(s.y, 16);
    s.z += __shfl_xor(s.z, 16); s.w += __shfl_xor(s.w, 16);
    s.x += __shfl_xor(s.x, 32); s.y += __shfl_xor(s.y, 32);
    s.z += __shfl_xor(s.z, 32); s.w += __shfl_xor(s.w, 32);

    if (g == 0) {
        size_t idx = (size_t)node * kRow4 + q;
        if (writeH) h4[idx] = s;
        float4 a = accIn4[idx];
        a.x = (a.x + s.x) * scale;
        a.y = (a.y + s.y) * scale;
        a.z = (a.z + s.z) * scale;
        a.w = (a.w + s.w) * scale;
        accOut4[idx] = a;
    }
}

// ---------------- launch ----------------

extern "C" void kernel_launch(void* const* d_in, const int* in_sizes, int n_in,
                              void* d_out, int out_size, void* d_ws, size_t ws_size,
                              hipStream_t stream) {
    const int*   edge  = (const int*)d_in[0];
    const int*   src   = edge;
    const int*   dst   = edge + kEdges;
    const float* emb_w = (const float*)d_in[1];
    float*       out   = (float*)d_out;

    // Workspace layout (re-poisoned 0xAA each call):
    //   counts : @0          600000
    //   dinv   : @600000     600000
    //   off    : @1200000    600000
    //   cur    : @1800000    600000
    //   sums   : @2400000    2352 (pad)
    //   pairs  : @2402352    8,000,000
    //   embA   : @10402352   38,400,000
    //   embB   : @48802352   38,400,000
    char*  ws     = (char*)d_ws;
    int*   counts = (int*)(ws);
    float* dinv   = (float*)(ws + 600000);
    int*   off    = (int*)(ws + 1200000);
    int*   cur    = (int*)(ws + 1800000);
    int*   sums   = (int*)(ws + 2400000);
    int2*  pairs  = (int2*)(ws + 2402352);
    float* embA   = (float*)(ws + 10402352);
    float* embB   = (float*)(ws + 48802352);

    const int edgeBlocks   = (kEdges + 255) / 256;
    const int nodeBlocks   = kScanBlk;
    const int gatherBlocks = (kNodes * kDim) / 256;  // 37500, exact

    // CSR build
    hipMemsetAsync(counts, 0, (size_t)kNodes * 4, stream);
    hist_kernel<<<edgeBlocks, 256, 0, stream>>>(dst, counts);
    scan_block_kernel<<<nodeBlocks, 256, 0, stream>>>(counts, off, sums);
    scan_sums_kernel<<<1, 1024, 0, stream>>>(sums);
    scan_fixup_kernel<<<nodeBlocks, 256, 0, stream>>>(off, cur, sums, counts, dinv);
    fill_kernel<<<edgeBlocks, 256, 0, stream>>>(src, dst, dinv, cur, pairs);

    // Layer 1: h1 = conv(emb_w); out = emb_w + h1
    gather_kernel<<<gatherBlocks, 256, 0, stream>>>(off, counts, pairs,
                                                    (const float4*)emb_w, (float4*)embA,
                                                    (const float4*)emb_w, (float4*)out,
                                                    1.0f, 1);
    // Layer 2: h2 = conv(h1); out += h2
    gather_kernel<<<gatherBlocks, 256, 0, stream>>>(off, counts, pairs,
                                                    (const float4*)embA, (float4*)embB,
                                                    (const float4*)out, (float4*)out,
                                                    1.0f, 1);
    // Layer 3: h3 = conv(h2); out = (out + h3) / 4
    gather_kernel<<<gatherBlocks, 256, 0, stream>>>(off, counts, pairs,
                                                    (const float4*)embB, (float4*)embA,
                                                    (const float4*)out, (float4*)out,
                                                    0.25f, 0);
}